// Round 1
// baseline (1271.759 us; speedup 1.0000x reference)
//
#include <hip/hip_runtime.h>
#include <hip/hip_bf16.h>

#define NNODES 100000
#define NEDGES 640000
#define DIM 128
#define NG 8
#define GS 16

// ---------------------------------------------------------------- zero init
__global__ void zero_kernel(float* __restrict__ out, float* __restrict__ count) {
    long step = (long)gridDim.x * blockDim.x;
    long i0 = (long)blockIdx.x * blockDim.x + threadIdx.x;
    const long total = (long)NNODES * DIM;
    for (long i = i0; i < total; i += step) out[i] = 0.f;
    for (long i = i0; i < NNODES; i += step) count[i] = 0.f;
}

// ---------------------------------------------------------------- node GEMM
// xa = x @ W1[0:128,:],  xb = x @ W1[128:256,:]   (both [NNODES,128])
__global__ __launch_bounds__(256) void node_gemm(const float* __restrict__ x,
                                                 const float* __restrict__ W1,
                                                 float* __restrict__ xa,
                                                 float* __restrict__ xb) {
    __shared__ float lds_x[32][33];     // 32 nodes x 32 k (padded)
    __shared__ float lds_wa[32][128];   // k-tile x channels
    __shared__ float lds_wb[32][128];
    const int tid = threadIdx.x;
    const int n0 = (tid >> 5) * 4;      // node offset in tile: 0..28
    const int c0 = (tid & 31) * 4;      // channel offset: 0..124
    const int nodeBase = blockIdx.x * 32;

    float acca[4][4] = {{0.f}};
    float accb[4][4] = {{0.f}};

    for (int kt = 0; kt < 4; ++kt) {
        // stage x tile: 32 nodes x 32 k
        {
            int n = tid >> 3;               // 0..31
            int k = (tid & 7) * 4;          // 0..28
            float4 v = *(const float4*)&x[(long)(nodeBase + n) * DIM + kt * 32 + k];
            lds_x[n][k + 0] = v.x; lds_x[n][k + 1] = v.y;
            lds_x[n][k + 2] = v.z; lds_x[n][k + 3] = v.w;
        }
        // stage W tiles: 32 k x 128 c, both halves
        #pragma unroll
        for (int r = 0; r < 4; ++r) {
            int idx = r * 256 + tid;        // float4 index 0..1023
            int kk = idx >> 5;
            int cc = (idx & 31) * 4;
            *(float4*)&lds_wa[kk][cc] = *(const float4*)&W1[(long)(kt * 32 + kk) * DIM + cc];
            *(float4*)&lds_wb[kk][cc] = *(const float4*)&W1[(long)(128 + kt * 32 + kk) * DIM + cc];
        }
        __syncthreads();
        #pragma unroll 8
        for (int kk = 0; kk < 32; ++kk) {
            float4 wa = *(float4*)&lds_wa[kk][c0];
            float4 wb = *(float4*)&lds_wb[kk][c0];
            #pragma unroll
            for (int i = 0; i < 4; ++i) {
                float xv = lds_x[n0 + i][kk];
                acca[i][0] += xv * wa.x; acca[i][1] += xv * wa.y;
                acca[i][2] += xv * wa.z; acca[i][3] += xv * wa.w;
                accb[i][0] += xv * wb.x; accb[i][1] += xv * wb.y;
                accb[i][2] += xv * wb.z; accb[i][3] += xv * wb.w;
            }
        }
        __syncthreads();
    }
    #pragma unroll
    for (int i = 0; i < 4; ++i) {
        long base = (long)(nodeBase + n0 + i) * DIM + c0;
        float4 va = {acca[i][0], acca[i][1], acca[i][2], acca[i][3]};
        float4 vb = {accb[i][0], accb[i][1], accb[i][2], accb[i][3]};
        *(float4*)&xa[base] = va;
        *(float4*)&xb[base] = vb;
    }
}

// ---------------------------------------------------------------- edge counts
__global__ void count_kernel(const int* __restrict__ ei, float* __restrict__ count) {
    int e = blockIdx.x * 256 + threadIdx.x;
    if (e < NEDGES) unsafeAtomicAdd(&count[ei[NEDGES + e]], 1.0f);
}

// ---------------------------------------------------------------- edge phase
// h = xa[dst] + xb[src] + ea@W1c + b1 ; GN ; SiLU ; @W2 + b2 ; atomic scatter
__global__ __launch_bounds__(256) void edge_kernel(
    const float* __restrict__ xa, const float* __restrict__ xb,
    const int* __restrict__ ei, const float* __restrict__ ea,
    const float* __restrict__ W1, const float* __restrict__ b1,
    const float* __restrict__ gamma, const float* __restrict__ beta,
    const float* __restrict__ W2, const float* __restrict__ b2,
    float* __restrict__ out)
{
    __shared__ float s_tile[32][129];   // h, then silu(gn(h)) in place
    __shared__ float w2t[32][128];      // W2 k-tile
    __shared__ float w1c[4][128];
    __shared__ float sb1[128], sg[128], sbt[128], sb2[128];
    __shared__ int   sdst[32], ssrc[32];
    __shared__ float sea[32][4];

    const int tid = threadIdx.x;
    const int e0 = blockIdx.x * 32;

    if (tid < 128) {
        sb1[tid] = b1[tid]; sg[tid] = gamma[tid]; sbt[tid] = beta[tid]; sb2[tid] = b2[tid];
        w1c[0][tid] = W1[256 * DIM + tid];
        w1c[1][tid] = W1[257 * DIM + tid];
        w1c[2][tid] = W1[258 * DIM + tid];
        w1c[3][tid] = W1[259 * DIM + tid];
        ((float*)sea)[tid] = ea[(long)e0 * 4 + tid];
    }
    if (tid < 32) { sdst[tid] = ei[NEDGES + e0 + tid]; ssrc[tid] = ei[e0 + tid]; }
    __syncthreads();

    // h tile: 32 edges x 128 channels, float4 per thread x 4 iters
    #pragma unroll
    for (int j = 0; j < 4; ++j) {
        int idx = j * 256 + tid;        // float4 index 0..1023
        int e = idx >> 5;
        int c = (idx & 31) * 4;
        float4 va = *(const float4*)&xa[(long)sdst[e] * DIM + c];
        float4 vb = *(const float4*)&xb[(long)ssrc[e] * DIM + c];
        float a0 = sea[e][0], a1 = sea[e][1], a2 = sea[e][2], a3 = sea[e][3];
        float h0 = va.x + vb.x + sb1[c + 0] + a0 * w1c[0][c + 0] + a1 * w1c[1][c + 0] + a2 * w1c[2][c + 0] + a3 * w1c[3][c + 0];
        float h1 = va.y + vb.y + sb1[c + 1] + a0 * w1c[0][c + 1] + a1 * w1c[1][c + 1] + a2 * w1c[2][c + 1] + a3 * w1c[3][c + 1];
        float h2 = va.z + vb.z + sb1[c + 2] + a0 * w1c[0][c + 2] + a1 * w1c[1][c + 2] + a2 * w1c[2][c + 2] + a3 * w1c[3][c + 2];
        float h3 = va.w + vb.w + sb1[c + 3] + a0 * w1c[0][c + 3] + a1 * w1c[1][c + 3] + a2 * w1c[2][c + 3] + a3 * w1c[3][c + 3];
        s_tile[e][c + 0] = h0; s_tile[e][c + 1] = h1;
        s_tile[e][c + 2] = h2; s_tile[e][c + 3] = h3;
    }
    __syncthreads();

    // GroupNorm + SiLU: one (edge, group) per thread: 32*8 = 256
    {
        int e = tid >> 3, g = tid & 7;
        float vals[GS];
        float sum = 0.f;
        #pragma unroll
        for (int i = 0; i < GS; ++i) { vals[i] = s_tile[e][g * GS + i]; sum += vals[i]; }
        float mean = sum * (1.f / GS);
        float var = 0.f;
        #pragma unroll
        for (int i = 0; i < GS; ++i) { float d = vals[i] - mean; var += d * d; }
        var *= (1.f / GS);
        float inv = rsqrtf(var + 1e-5f);
        #pragma unroll
        for (int i = 0; i < GS; ++i) {
            int c = g * GS + i;
            float v = (vals[i] - mean) * inv * sg[c] + sbt[c];
            s_tile[e][c] = v / (1.f + __expf(-v));   // SiLU
        }
    }
    __syncthreads();

    // GEMM2: [32 edges x 128] @ W2[128x128], 4x4 micro-tile per thread
    const int r0 = (tid >> 5) * 4;
    const int c0 = (tid & 31) * 4;
    float acc[4][4] = {{0.f}};
    for (int kt = 0; kt < 4; ++kt) {
        #pragma unroll
        for (int r = 0; r < 4; ++r) {
            int idx = r * 256 + tid;
            int kk = idx >> 5;
            int cc = (idx & 31) * 4;
            *(float4*)&w2t[kk][cc] = *(const float4*)&W2[(long)(kt * 32 + kk) * DIM + cc];
        }
        __syncthreads();
        #pragma unroll 8
        for (int kk = 0; kk < 32; ++kk) {
            float4 w = *(float4*)&w2t[kk][c0];
            #pragma unroll
            for (int i = 0; i < 4; ++i) {
                float sv = s_tile[r0 + i][kt * 32 + kk];
                acc[i][0] += sv * w.x; acc[i][1] += sv * w.y;
                acc[i][2] += sv * w.z; acc[i][3] += sv * w.w;
            }
        }
        __syncthreads();
    }

    // scatter messages (+b2) to out[dst]
    #pragma unroll
    for (int i = 0; i < 4; ++i) {
        int e = r0 + i;
        long base = (long)sdst[e] * DIM + c0;
        unsafeAtomicAdd(&out[base + 0], acc[i][0] + sb2[c0 + 0]);
        unsafeAtomicAdd(&out[base + 1], acc[i][1] + sb2[c0 + 1]);
        unsafeAtomicAdd(&out[base + 2], acc[i][2] + sb2[c0 + 2]);
        unsafeAtomicAdd(&out[base + 3], acc[i][3] + sb2[c0 + 3]);
    }
}

// ---------------------------------------------------------------- finalize
__global__ void finalize_kernel(float* __restrict__ out, const float* __restrict__ count) {
    long i = (long)blockIdx.x * 256 + threadIdx.x;
    if (i < (long)NNODES * DIM) {
        float c = count[i >> 7];
        out[i] = out[i] / fmaxf(c, 1.f);
    }
}

// ---------------------------------------------------------------- launch
extern "C" void kernel_launch(void* const* d_in, const int* in_sizes, int n_in,
                              void* d_out, int out_size, void* d_ws, size_t ws_size,
                              hipStream_t stream) {
    const float* x     = (const float*)d_in[0];
    const int*   ei    = (const int*)  d_in[1];
    const float* ea    = (const float*)d_in[2];
    const float* W1    = (const float*)d_in[3];
    const float* b1    = (const float*)d_in[4];
    const float* gamma = (const float*)d_in[5];
    const float* beta  = (const float*)d_in[6];
    const float* W2    = (const float*)d_in[7];
    const float* b2    = (const float*)d_in[8];
    float* out = (float*)d_out;

    char* ws = (char*)d_ws;
    float* xa    = (float*)ws;
    float* xb    = (float*)(ws + (size_t)NNODES * DIM * sizeof(float));
    float* count = (float*)(ws + 2 * (size_t)NNODES * DIM * sizeof(float));

    zero_kernel<<<2048, 256, 0, stream>>>(out, count);
    node_gemm<<<NNODES / 32, 256, 0, stream>>>(x, W1, xa, xb);            // 3125 blocks
    count_kernel<<<(NEDGES + 255) / 256, 256, 0, stream>>>(ei, count);
    edge_kernel<<<NEDGES / 32, 256, 0, stream>>>(xa, xb, ei, ea, W1, b1,
                                                 gamma, beta, W2, b2, out); // 20000 blocks
    finalize_kernel<<<(NNODES * DIM + 255) / 256, 256, 0, stream>>>(out, count);
}

// Round 2
// 661.390 us; speedup vs baseline: 1.9229x; 1.9229x over previous
//
#include <hip/hip_runtime.h>
#include <hip/hip_bf16.h>

#define NNODES 100000
#define NEDGES 640000
#define DIM 128
#define NG 8
#define GS 16
#define NSCAN_BLOCKS ((NNODES + 255) / 256)   // 391

// ---------------------------------------------------------------- zero init
__global__ void zero_kernel(float* __restrict__ out, int* __restrict__ hist) {
    long step = (long)gridDim.x * blockDim.x;
    long i0 = (long)blockIdx.x * blockDim.x + threadIdx.x;
    const long total = (long)NNODES * DIM;
    for (long i = i0; i < total; i += step) out[i] = 0.f;
    for (long i = i0; i < NNODES; i += step) hist[i] = 0;
}

// ---------------------------------------------------------------- node GEMM
// xa = x @ W1[0:128,:],  xb = x @ W1[128:256,:]   (both [NNODES,128])
__global__ __launch_bounds__(256) void node_gemm(const float* __restrict__ x,
                                                 const float* __restrict__ W1,
                                                 float* __restrict__ xa,
                                                 float* __restrict__ xb) {
    __shared__ float lds_x[32][33];
    __shared__ float lds_wa[32][128];
    __shared__ float lds_wb[32][128];
    const int tid = threadIdx.x;
    const int n0 = (tid >> 5) * 4;
    const int c0 = (tid & 31) * 4;
    const int nodeBase = blockIdx.x * 32;

    float acca[4][4] = {{0.f}};
    float accb[4][4] = {{0.f}};

    for (int kt = 0; kt < 4; ++kt) {
        {
            int n = tid >> 3;
            int k = (tid & 7) * 4;
            float4 v = *(const float4*)&x[(long)(nodeBase + n) * DIM + kt * 32 + k];
            lds_x[n][k + 0] = v.x; lds_x[n][k + 1] = v.y;
            lds_x[n][k + 2] = v.z; lds_x[n][k + 3] = v.w;
        }
        #pragma unroll
        for (int r = 0; r < 4; ++r) {
            int idx = r * 256 + tid;
            int kk = idx >> 5;
            int cc = (idx & 31) * 4;
            *(float4*)&lds_wa[kk][cc] = *(const float4*)&W1[(long)(kt * 32 + kk) * DIM + cc];
            *(float4*)&lds_wb[kk][cc] = *(const float4*)&W1[(long)(128 + kt * 32 + kk) * DIM + cc];
        }
        __syncthreads();
        #pragma unroll 8
        for (int kk = 0; kk < 32; ++kk) {
            float4 wa = *(float4*)&lds_wa[kk][c0];
            float4 wb = *(float4*)&lds_wb[kk][c0];
            #pragma unroll
            for (int i = 0; i < 4; ++i) {
                float xv = lds_x[n0 + i][kk];
                acca[i][0] += xv * wa.x; acca[i][1] += xv * wa.y;
                acca[i][2] += xv * wa.z; acca[i][3] += xv * wa.w;
                accb[i][0] += xv * wb.x; accb[i][1] += xv * wb.y;
                accb[i][2] += xv * wb.z; accb[i][3] += xv * wb.w;
            }
        }
        __syncthreads();
    }
    #pragma unroll
    for (int i = 0; i < 4; ++i) {
        long base = (long)(nodeBase + n0 + i) * DIM + c0;
        float4 va = {acca[i][0], acca[i][1], acca[i][2], acca[i][3]};
        float4 vb = {accb[i][0], accb[i][1], accb[i][2], accb[i][3]};
        *(float4*)&xa[base] = va;
        *(float4*)&xb[base] = vb;
    }
}

// ---------------------------------------------------------------- histogram
__global__ void hist_kernel(const int* __restrict__ ei, int* __restrict__ hist) {
    int e = blockIdx.x * 256 + threadIdx.x;
    if (e < NEDGES) atomicAdd(&hist[ei[NEDGES + e]], 1);
}

// ---------------------------------------------------------------- 2-level scan
__global__ void scan1_kernel(const int* __restrict__ hist, int* __restrict__ excl,
                             int* __restrict__ bsums) {
    __shared__ int s[256];
    int tid = threadIdx.x;
    int i = blockIdx.x * 256 + tid;
    int v = (i < NNODES) ? hist[i] : 0;
    s[tid] = v;
    __syncthreads();
    for (int o = 1; o < 256; o <<= 1) {
        int t = (tid >= o) ? s[tid - o] : 0;
        __syncthreads();
        s[tid] += t;
        __syncthreads();
    }
    if (i < NNODES) excl[i] = s[tid] - v;
    if (tid == 255) bsums[blockIdx.x] = s[255];
}

__global__ void scan2_kernel(int* __restrict__ bsums) {
    __shared__ int s[512];
    int tid = threadIdx.x;
    int v = (tid < NSCAN_BLOCKS) ? bsums[tid] : 0;
    s[tid] = v;
    __syncthreads();
    for (int o = 1; o < 512; o <<= 1) {
        int t = (tid >= o) ? s[tid - o] : 0;
        __syncthreads();
        s[tid] += t;
        __syncthreads();
    }
    if (tid < NSCAN_BLOCKS) bsums[tid] = s[tid] - v;   // exclusive
}

__global__ void scan3_kernel(const int* __restrict__ excl, const int* __restrict__ bsums,
                             int* __restrict__ cursor) {
    int i = blockIdx.x * 256 + threadIdx.x;
    if (i < NNODES) cursor[i] = excl[i] + bsums[blockIdx.x];
}

// ---------------------------------------------------------------- scatter (counting sort)
__global__ void scatter_kernel(const int* __restrict__ ei, int* __restrict__ cursor,
                               int* __restrict__ sorted) {
    int e = blockIdx.x * 256 + threadIdx.x;
    if (e < NEDGES) {
        int d = ei[NEDGES + e];
        int pos = atomicAdd(&cursor[d], 1);
        sorted[pos] = e;
    }
}

// ---------------------------------------------------------------- edge phase (dst-sorted)
__global__ __launch_bounds__(256) void edge_kernel(
    const float* __restrict__ xa, const float* __restrict__ xb,
    const int* __restrict__ ei, const float* __restrict__ ea,
    const int* __restrict__ sorted,
    const float* __restrict__ W1, const float* __restrict__ b1,
    const float* __restrict__ gamma, const float* __restrict__ beta,
    const float* __restrict__ W2, const float* __restrict__ b2,
    float* __restrict__ out)
{
    __shared__ float s_tile[32][129];
    __shared__ float w2t[32][128];
    __shared__ float w1c[4][128];
    __shared__ float sb1[128], sg[128], sbt[128], sb2[128];
    __shared__ int   sdst[32], ssrc[32], seid[32];
    __shared__ float sea[32][4];

    const int tid = threadIdx.x;
    const int e0 = blockIdx.x * 32;

    if (tid < 32) seid[tid] = sorted[e0 + tid];
    __syncthreads();
    if (tid < 32) { sdst[tid] = ei[NEDGES + seid[tid]]; ssrc[tid] = ei[seid[tid]]; }
    if (tid < 128) {
        sb1[tid] = b1[tid]; sg[tid] = gamma[tid]; sbt[tid] = beta[tid]; sb2[tid] = b2[tid];
        w1c[0][tid] = W1[256 * DIM + tid];
        w1c[1][tid] = W1[257 * DIM + tid];
        w1c[2][tid] = W1[258 * DIM + tid];
        w1c[3][tid] = W1[259 * DIM + tid];
        int e = tid >> 2, comp = tid & 3;
        sea[e][comp] = ea[(long)seid[e] * 4 + comp];
    }
    __syncthreads();

    // h tile: 32 edges x 128 channels
    #pragma unroll
    for (int j = 0; j < 4; ++j) {
        int idx = j * 256 + tid;
        int e = idx >> 5;
        int c = (idx & 31) * 4;
        float4 va = *(const float4*)&xa[(long)sdst[e] * DIM + c];
        float4 vb = *(const float4*)&xb[(long)ssrc[e] * DIM + c];
        float a0 = sea[e][0], a1 = sea[e][1], a2 = sea[e][2], a3 = sea[e][3];
        float h0 = va.x + vb.x + sb1[c + 0] + a0 * w1c[0][c + 0] + a1 * w1c[1][c + 0] + a2 * w1c[2][c + 0] + a3 * w1c[3][c + 0];
        float h1 = va.y + vb.y + sb1[c + 1] + a0 * w1c[0][c + 1] + a1 * w1c[1][c + 1] + a2 * w1c[2][c + 1] + a3 * w1c[3][c + 1];
        float h2 = va.z + vb.z + sb1[c + 2] + a0 * w1c[0][c + 2] + a1 * w1c[1][c + 2] + a2 * w1c[2][c + 2] + a3 * w1c[3][c + 2];
        float h3 = va.w + vb.w + sb1[c + 3] + a0 * w1c[0][c + 3] + a1 * w1c[1][c + 3] + a2 * w1c[2][c + 3] + a3 * w1c[3][c + 3];
        s_tile[e][c + 0] = h0; s_tile[e][c + 1] = h1;
        s_tile[e][c + 2] = h2; s_tile[e][c + 3] = h3;
    }
    __syncthreads();

    // GroupNorm + SiLU
    {
        int e = tid >> 3, g = tid & 7;
        float vals[GS];
        float sum = 0.f;
        #pragma unroll
        for (int i = 0; i < GS; ++i) { vals[i] = s_tile[e][g * GS + i]; sum += vals[i]; }
        float mean = sum * (1.f / GS);
        float var = 0.f;
        #pragma unroll
        for (int i = 0; i < GS; ++i) { float d = vals[i] - mean; var += d * d; }
        var *= (1.f / GS);
        float inv = rsqrtf(var + 1e-5f);
        #pragma unroll
        for (int i = 0; i < GS; ++i) {
            int c = g * GS + i;
            float v = (vals[i] - mean) * inv * sg[c] + sbt[c];
            s_tile[e][c] = v / (1.f + __expf(-v));
        }
    }
    __syncthreads();

    // GEMM2: [32 x 128] @ W2[128 x 128]
    const int r0 = (tid >> 5) * 4;
    const int c0 = (tid & 31) * 4;
    float acc[4][4] = {{0.f}};
    for (int kt = 0; kt < 4; ++kt) {
        #pragma unroll
        for (int r = 0; r < 4; ++r) {
            int idx = r * 256 + tid;
            int kk = idx >> 5;
            int cc = (idx & 31) * 4;
            *(float4*)&w2t[kk][cc] = *(const float4*)&W2[(long)(kt * 32 + kk) * DIM + cc];
        }
        __syncthreads();
        #pragma unroll 8
        for (int kk = 0; kk < 32; ++kk) {
            float4 w = *(float4*)&w2t[kk][c0];
            #pragma unroll
            for (int i = 0; i < 4; ++i) {
                float sv = s_tile[r0 + i][kt * 32 + kk];
                acc[i][0] += sv * w.x; acc[i][1] += sv * w.y;
                acc[i][2] += sv * w.z; acc[i][3] += sv * w.w;
            }
        }
        __syncthreads();
    }

    // add b2, merge consecutive same-dst rows in registers, then atomic scatter
    #pragma unroll
    for (int i = 0; i < 4; ++i) {
        acc[i][0] += sb2[c0 + 0]; acc[i][1] += sb2[c0 + 1];
        acc[i][2] += sb2[c0 + 2]; acc[i][3] += sb2[c0 + 3];
    }
    #pragma unroll
    for (int i = 0; i < 4; ++i) {
        int e = r0 + i;
        if (i < 3 && sdst[e] == sdst[e + 1]) {
            acc[i + 1][0] += acc[i][0]; acc[i + 1][1] += acc[i][1];
            acc[i + 1][2] += acc[i][2]; acc[i + 1][3] += acc[i][3];
        } else {
            long base = (long)sdst[e] * DIM + c0;
            unsafeAtomicAdd(&out[base + 0], acc[i][0]);
            unsafeAtomicAdd(&out[base + 1], acc[i][1]);
            unsafeAtomicAdd(&out[base + 2], acc[i][2]);
            unsafeAtomicAdd(&out[base + 3], acc[i][3]);
        }
    }
}

// ---------------------------------------------------------------- finalize
__global__ void finalize_kernel(float* __restrict__ out, const int* __restrict__ hist) {
    long i = (long)blockIdx.x * 256 + threadIdx.x;
    if (i < (long)NNODES * DIM) {
        float c = (float)hist[i >> 7];
        out[i] = out[i] / fmaxf(c, 1.f);
    }
}

// ---------------------------------------------------------------- launch
extern "C" void kernel_launch(void* const* d_in, const int* in_sizes, int n_in,
                              void* d_out, int out_size, void* d_ws, size_t ws_size,
                              hipStream_t stream) {
    const float* x     = (const float*)d_in[0];
    const int*   ei    = (const int*)  d_in[1];
    const float* ea    = (const float*)d_in[2];
    const float* W1    = (const float*)d_in[3];
    const float* b1    = (const float*)d_in[4];
    const float* gamma = (const float*)d_in[5];
    const float* beta  = (const float*)d_in[6];
    const float* W2    = (const float*)d_in[7];
    const float* b2    = (const float*)d_in[8];
    float* out = (float*)d_out;

    char* ws = (char*)d_ws;
    size_t off = 0;
    float* xa     = (float*)(ws + off); off += (size_t)NNODES * DIM * sizeof(float);
    float* xb     = (float*)(ws + off); off += (size_t)NNODES * DIM * sizeof(float);
    int*   hist   = (int*)  (ws + off); off += (size_t)NNODES * sizeof(int);
    int*   excl   = (int*)  (ws + off); off += (size_t)NNODES * sizeof(int);
    int*   cursor = (int*)  (ws + off); off += (size_t)NNODES * sizeof(int);
    int*   bsums  = (int*)  (ws + off); off += 512 * sizeof(int);
    int*   sorted = (int*)  (ws + off); off += (size_t)NEDGES * sizeof(int);

    zero_kernel<<<2048, 256, 0, stream>>>(out, hist);
    node_gemm<<<NNODES / 32, 256, 0, stream>>>(x, W1, xa, xb);
    hist_kernel<<<(NEDGES + 255) / 256, 256, 0, stream>>>(ei, hist);
    scan1_kernel<<<NSCAN_BLOCKS, 256, 0, stream>>>(hist, excl, bsums);
    scan2_kernel<<<1, 512, 0, stream>>>(bsums);
    scan3_kernel<<<NSCAN_BLOCKS, 256, 0, stream>>>(excl, bsums, cursor);
    scatter_kernel<<<(NEDGES + 255) / 256, 256, 0, stream>>>(ei, cursor, sorted);
    edge_kernel<<<NEDGES / 32, 256, 0, stream>>>(xa, xb, ei, ea, sorted, W1, b1,
                                                 gamma, beta, W2, b2, out);
    finalize_kernel<<<(NNODES * DIM + 255) / 256, 256, 0, stream>>>(out, hist);
}

// Round 3
// 365.710 us; speedup vs baseline: 3.4775x; 1.8085x over previous
//
#include <hip/hip_runtime.h>
#include <hip/hip_bf16.h>

#define NNODES 100000
#define NEDGES 640000
#define DIM 128
#define GS 16
#define EB 64                                  // edges per block
#define NSCAN_BLOCKS ((NNODES + 255) / 256)    // 391

// ---------------------------------------------------------------- zero init
__global__ void zero_kernel(float* __restrict__ out, int* __restrict__ hist) {
    long step = (long)gridDim.x * blockDim.x;
    long i0 = (long)blockIdx.x * blockDim.x + threadIdx.x;
    const long total = (long)NNODES * DIM;
    for (long i = i0; i < total; i += step) out[i] = 0.f;
    for (long i = i0; i < NNODES; i += step) hist[i] = 0;
}

// ---------------------------------------------------------------- node GEMM
// xa = x @ W1[0:128,:],  xb = x @ W1[128:256,:]   (both [NNODES,128])
__global__ __launch_bounds__(256) void node_gemm(const float* __restrict__ x,
                                                 const float* __restrict__ W1,
                                                 float* __restrict__ xa,
                                                 float* __restrict__ xb) {
    __shared__ float lds_x[32][33];
    __shared__ float lds_wa[32][128];
    __shared__ float lds_wb[32][128];
    const int tid = threadIdx.x;
    const int n0 = (tid >> 5) * 4;
    const int c0 = (tid & 31) * 4;
    const int nodeBase = blockIdx.x * 32;

    float acca[4][4] = {{0.f}};
    float accb[4][4] = {{0.f}};

    for (int kt = 0; kt < 4; ++kt) {
        {
            int n = tid >> 3;
            int k = (tid & 7) * 4;
            float4 v = *(const float4*)&x[(long)(nodeBase + n) * DIM + kt * 32 + k];
            lds_x[n][k + 0] = v.x; lds_x[n][k + 1] = v.y;
            lds_x[n][k + 2] = v.z; lds_x[n][k + 3] = v.w;
        }
        #pragma unroll
        for (int r = 0; r < 4; ++r) {
            int idx = r * 256 + tid;
            int kk = idx >> 5;
            int cc = (idx & 31) * 4;
            *(float4*)&lds_wa[kk][cc] = *(const float4*)&W1[(long)(kt * 32 + kk) * DIM + cc];
            *(float4*)&lds_wb[kk][cc] = *(const float4*)&W1[(long)(128 + kt * 32 + kk) * DIM + cc];
        }
        __syncthreads();
        #pragma unroll 8
        for (int kk = 0; kk < 32; ++kk) {
            float4 wa = *(float4*)&lds_wa[kk][c0];
            float4 wb = *(float4*)&lds_wb[kk][c0];
            #pragma unroll
            for (int i = 0; i < 4; ++i) {
                float xv = lds_x[n0 + i][kk];
                acca[i][0] += xv * wa.x; acca[i][1] += xv * wa.y;
                acca[i][2] += xv * wa.z; acca[i][3] += xv * wa.w;
                accb[i][0] += xv * wb.x; accb[i][1] += xv * wb.y;
                accb[i][2] += xv * wb.z; accb[i][3] += xv * wb.w;
            }
        }
        __syncthreads();
    }
    #pragma unroll
    for (int i = 0; i < 4; ++i) {
        long base = (long)(nodeBase + n0 + i) * DIM + c0;
        float4 va = {acca[i][0], acca[i][1], acca[i][2], acca[i][3]};
        float4 vb = {accb[i][0], accb[i][1], accb[i][2], accb[i][3]};
        *(float4*)&xa[base] = va;
        *(float4*)&xb[base] = vb;
    }
}

// ---------------------------------------------------------------- histogram
__global__ void hist_kernel(const int* __restrict__ ei, int* __restrict__ hist) {
    int e = blockIdx.x * 256 + threadIdx.x;
    if (e < NEDGES) atomicAdd(&hist[ei[NEDGES + e]], 1);
}

// ---------------------------------------------------------------- 2-level scan
__global__ void scan1_kernel(const int* __restrict__ hist, int* __restrict__ excl,
                             int* __restrict__ bsums) {
    __shared__ int s[256];
    int tid = threadIdx.x;
    int i = blockIdx.x * 256 + tid;
    int v = (i < NNODES) ? hist[i] : 0;
    s[tid] = v;
    __syncthreads();
    for (int o = 1; o < 256; o <<= 1) {
        int t = (tid >= o) ? s[tid - o] : 0;
        __syncthreads();
        s[tid] += t;
        __syncthreads();
    }
    if (i < NNODES) excl[i] = s[tid] - v;
    if (tid == 255) bsums[blockIdx.x] = s[255];
}

__global__ void scan2_kernel(int* __restrict__ bsums) {
    __shared__ int s[512];
    int tid = threadIdx.x;
    int v = (tid < NSCAN_BLOCKS) ? bsums[tid] : 0;
    s[tid] = v;
    __syncthreads();
    for (int o = 1; o < 512; o <<= 1) {
        int t = (tid >= o) ? s[tid - o] : 0;
        __syncthreads();
        s[tid] += t;
        __syncthreads();
    }
    if (tid < NSCAN_BLOCKS) bsums[tid] = s[tid] - v;   // exclusive
}

__global__ void scan3_kernel(const int* __restrict__ excl, const int* __restrict__ bsums,
                             int* __restrict__ cursor) {
    int i = blockIdx.x * 256 + threadIdx.x;
    if (i < NNODES) cursor[i] = excl[i] + bsums[blockIdx.x];
}

// ---------------------------------------------------------------- scatter (counting sort)
__global__ void scatter_kernel(const int* __restrict__ ei, int* __restrict__ cursor,
                               int* __restrict__ sorted) {
    int e = blockIdx.x * 256 + threadIdx.x;
    if (e < NEDGES) {
        int d = ei[NEDGES + e];
        int pos = atomicAdd(&cursor[d], 1);
        sorted[pos] = e;
    }
}

// ---------------------------------------------------------------- edge phase
// h = xa[dst]+xb[src]+ea@W1c+b1 ; GN ; SiLU ; segmented-sum by dst -> atomic to out(acc)
__global__ __launch_bounds__(256) void edge_silu_kernel(
    const float* __restrict__ xa, const float* __restrict__ xb,
    const int* __restrict__ ei, const float* __restrict__ ea,
    const int* __restrict__ sorted,
    const float* __restrict__ W1, const float* __restrict__ b1,
    const float* __restrict__ gamma, const float* __restrict__ beta,
    float* __restrict__ out)
{
    __shared__ float s_silu[EB][132];      // stride 132: walk phase is row-access, conflict-free
    __shared__ float w1c[4][128];
    __shared__ float sb1[128], sg[128], sbt[128];
    __shared__ int   sdst[EB], ssrc[EB], seid[EB];
    __shared__ float sea[EB][4];

    const int tid = threadIdx.x;
    const int e0 = blockIdx.x * EB;

    if (tid < EB) seid[tid] = sorted[e0 + tid];
    __syncthreads();
    if (tid < EB) {
        sdst[tid] = ei[NEDGES + seid[tid]];
        ssrc[tid] = ei[seid[tid]];
        *(float4*)&sea[tid][0] = *(const float4*)&ea[(long)seid[tid] * 4];
    }
    if (tid < 128) {
        sb1[tid] = b1[tid]; sg[tid] = gamma[tid]; sbt[tid] = beta[tid];
        w1c[0][tid] = W1[256 * DIM + tid];
        w1c[1][tid] = W1[257 * DIM + tid];
        w1c[2][tid] = W1[258 * DIM + tid];
        w1c[3][tid] = W1[259 * DIM + tid];
    }
    __syncthreads();

    // each thread: one edge (e = tid>>2), 32 consecutive channels (q = tid&3)
    {
        const int e = tid >> 2;
        const int c0 = (tid & 3) * 32;
        const float* xaRow = &xa[(long)sdst[e] * DIM + c0];
        const float* xbRow = &xb[(long)ssrc[e] * DIM + c0];
        const float a0 = sea[e][0], a1 = sea[e][1], a2 = sea[e][2], a3 = sea[e][3];

        float v[32];
        #pragma unroll
        for (int j = 0; j < 8; ++j) {
            float4 va = *(const float4*)&xaRow[j * 4];
            float4 vb = *(const float4*)&xbRow[j * 4];
            int c = c0 + j * 4;
            v[j*4+0] = va.x + vb.x + sb1[c+0] + a0*w1c[0][c+0] + a1*w1c[1][c+0] + a2*w1c[2][c+0] + a3*w1c[3][c+0];
            v[j*4+1] = va.y + vb.y + sb1[c+1] + a0*w1c[0][c+1] + a1*w1c[1][c+1] + a2*w1c[2][c+1] + a3*w1c[3][c+1];
            v[j*4+2] = va.z + vb.z + sb1[c+2] + a0*w1c[0][c+2] + a1*w1c[1][c+2] + a2*w1c[2][c+2] + a3*w1c[3][c+2];
            v[j*4+3] = va.w + vb.w + sb1[c+3] + a0*w1c[0][c+3] + a1*w1c[1][c+3] + a2*w1c[2][c+3] + a3*w1c[3][c+3];
        }

        // GroupNorm + SiLU: thread owns exactly 2 full groups of 16 channels
        #pragma unroll
        for (int g = 0; g < 2; ++g) {
            float sum = 0.f;
            #pragma unroll
            for (int i = 0; i < GS; ++i) sum += v[g * GS + i];
            float mean = sum * (1.f / GS);
            float var = 0.f;
            #pragma unroll
            for (int i = 0; i < GS; ++i) { float d = v[g * GS + i] - mean; var += d * d; }
            var *= (1.f / GS);
            float inv = rsqrtf(var + 1e-5f);
            #pragma unroll
            for (int i = 0; i < GS; ++i) {
                int c = c0 + g * GS + i;
                float t = (v[g * GS + i] - mean) * inv * sg[c] + sbt[c];
                v[g * GS + i] = t / (1.f + __expf(-t));
            }
        }
        #pragma unroll
        for (int j = 0; j < 8; ++j) {
            float4 w = {v[j*4+0], v[j*4+1], v[j*4+2], v[j*4+3]};
            *(float4*)&s_silu[e][c0 + j * 4] = w;
        }
    }
    __syncthreads();

    // segmented column-walk: thread = (channel c, half h); branch is lane-uniform
    {
        const int c = tid & 127;
        const int h = tid >> 7;
        const int eS = h * 32, eE = eS + 32;
        float r = 0.f;
        int cur = sdst[eS];
        for (int ee = eS; ee < eE; ++ee) {
            int d = sdst[ee];
            if (d != cur) {
                unsafeAtomicAdd(&out[(long)cur * DIM + c], r);
                r = 0.f; cur = d;
            }
            r += s_silu[ee][c];
        }
        unsafeAtomicAdd(&out[(long)cur * DIM + c], r);
    }
}

// ---------------------------------------------------------------- node GEMM2 (in-place on out)
// out[n] = (acc[n] @ W2 + cnt_n * b2) / max(cnt_n, 1),  acc == out (read-before-write per block)
__global__ __launch_bounds__(256) void node_gemm2(float* __restrict__ out,
                                                  const float* __restrict__ W2,
                                                  const float* __restrict__ b2,
                                                  const int* __restrict__ hist) {
    __shared__ float lds_a[32][33];
    __shared__ float lds_w[32][128];
    __shared__ float sb2[128];
    const int tid = threadIdx.x;
    const int n0 = (tid >> 5) * 4;
    const int c0 = (tid & 31) * 4;
    const int nodeBase = blockIdx.x * 32;

    if (tid < 128) sb2[tid] = b2[tid];

    float acc[4][4] = {{0.f}};

    for (int kt = 0; kt < 4; ++kt) {
        {
            int n = tid >> 3;
            int k = (tid & 7) * 4;
            float4 v = *(const float4*)&out[(long)(nodeBase + n) * DIM + kt * 32 + k];
            lds_a[n][k + 0] = v.x; lds_a[n][k + 1] = v.y;
            lds_a[n][k + 2] = v.z; lds_a[n][k + 3] = v.w;
        }
        #pragma unroll
        for (int r = 0; r < 4; ++r) {
            int idx = r * 256 + tid;
            int kk = idx >> 5;
            int cc = (idx & 31) * 4;
            *(float4*)&lds_w[kk][cc] = *(const float4*)&W2[(long)(kt * 32 + kk) * DIM + cc];
        }
        __syncthreads();
        #pragma unroll 8
        for (int kk = 0; kk < 32; ++kk) {
            float4 w = *(float4*)&lds_w[kk][c0];
            #pragma unroll
            for (int i = 0; i < 4; ++i) {
                float av = lds_a[n0 + i][kk];
                acc[i][0] += av * w.x; acc[i][1] += av * w.y;
                acc[i][2] += av * w.z; acc[i][3] += av * w.w;
            }
        }
        __syncthreads();
    }
    #pragma unroll
    for (int i = 0; i < 4; ++i) {
        int node = nodeBase + n0 + i;
        float cnt = (float)hist[node];
        float scale = 1.f / fmaxf(cnt, 1.f);
        long base = (long)node * DIM + c0;
        float4 o;
        o.x = (acc[i][0] + cnt * sb2[c0 + 0]) * scale;
        o.y = (acc[i][1] + cnt * sb2[c0 + 1]) * scale;
        o.z = (acc[i][2] + cnt * sb2[c0 + 2]) * scale;
        o.w = (acc[i][3] + cnt * sb2[c0 + 3]) * scale;
        *(float4*)&out[base] = o;
    }
}

// ---------------------------------------------------------------- launch
extern "C" void kernel_launch(void* const* d_in, const int* in_sizes, int n_in,
                              void* d_out, int out_size, void* d_ws, size_t ws_size,
                              hipStream_t stream) {
    const float* x     = (const float*)d_in[0];
    const int*   ei    = (const int*)  d_in[1];
    const float* ea    = (const float*)d_in[2];
    const float* W1    = (const float*)d_in[3];
    const float* b1    = (const float*)d_in[4];
    const float* gamma = (const float*)d_in[5];
    const float* beta  = (const float*)d_in[6];
    const float* W2    = (const float*)d_in[7];
    const float* b2    = (const float*)d_in[8];
    float* out = (float*)d_out;

    char* ws = (char*)d_ws;
    size_t off = 0;
    float* xa     = (float*)(ws + off); off += (size_t)NNODES * DIM * sizeof(float);
    float* xb     = (float*)(ws + off); off += (size_t)NNODES * DIM * sizeof(float);
    int*   hist   = (int*)  (ws + off); off += (size_t)NNODES * sizeof(int);
    int*   excl   = (int*)  (ws + off); off += (size_t)NNODES * sizeof(int);
    int*   cursor = (int*)  (ws + off); off += (size_t)NNODES * sizeof(int);
    int*   bsums  = (int*)  (ws + off); off += 512 * sizeof(int);
    int*   sorted = (int*)  (ws + off); off += (size_t)NEDGES * sizeof(int);

    zero_kernel<<<2048, 256, 0, stream>>>(out, hist);
    node_gemm<<<NNODES / 32, 256, 0, stream>>>(x, W1, xa, xb);
    hist_kernel<<<(NEDGES + 255) / 256, 256, 0, stream>>>(ei, hist);
    scan1_kernel<<<NSCAN_BLOCKS, 256, 0, stream>>>(hist, excl, bsums);
    scan2_kernel<<<1, 512, 0, stream>>>(bsums);
    scan3_kernel<<<NSCAN_BLOCKS, 256, 0, stream>>>(excl, bsums, cursor);
    scatter_kernel<<<(NEDGES + 255) / 256, 256, 0, stream>>>(ei, cursor, sorted);
    edge_silu_kernel<<<NEDGES / EB, 256, 0, stream>>>(xa, xb, ei, ea, sorted,
                                                      W1, b1, gamma, beta, out);
    node_gemm2<<<NNODES / 32, 256, 0, stream>>>(out, W2, b2, hist);
}

// Round 5
// 224.417 us; speedup vs baseline: 5.6670x; 1.6296x over previous
//
#include <hip/hip_runtime.h>
#include <hip/hip_bf16.h>

#define NNODES 100000
#define NEDGES 640000
#define DIM 128
#define GS 16
#define EB 64                                  // edges per block
#define NSCAN_BLOCKS ((NNODES + 255) / 256)    // 391
#define G1_BLOCKS ((NNODES + 63) / 64)         // 1563 (tail block: 32 rows)

typedef __attribute__((ext_vector_type(8))) short short8;
typedef __attribute__((ext_vector_type(4))) float f32x4;

__device__ __forceinline__ ushort f2bf(float f) {
    __hip_bfloat16 h = __float2bfloat16(f);
    return *reinterpret_cast<ushort*>(&h);
}
__device__ __forceinline__ float bf2f(ushort u) {
    union { unsigned int i; float f; } v; v.i = ((unsigned int)u) << 16; return v.f;
}

// ---------------------------------------------------------------- zero init
__global__ void zero_kernel(float* __restrict__ out, int* __restrict__ hist) {
    long step = (long)gridDim.x * blockDim.x;
    long i0 = (long)blockIdx.x * blockDim.x + threadIdx.x;
    const long total = (long)NNODES * DIM;
    for (long i = i0; i < total; i += step) out[i] = 0.f;
    for (long i = i0; i < NNODES; i += step) hist[i] = 0;
}

// ---------------------------------------------------------------- node GEMM1 (MFMA)
// xab[n][0:256] = x[n][0:128] @ [W1a | W1b]  (bf16 output)
// block: 64 nodes, 4 waves; wave w owns cols [w*64, w*64+64)
__global__ __launch_bounds__(256) void node_gemm1(const float* __restrict__ x,
                                                  const float* __restrict__ W1,
                                                  ushort* __restrict__ xab) {
    __shared__ __align__(16) char xt[64 * 256];   // 64 rows x 128 bf16, XOR-swizzled
    const int tid  = threadIdx.x;
    const int lane = tid & 63;
    const int w    = tid >> 6;
    const int lr   = lane & 15;     // row-in-tile (A) / col-in-tile (B,D)
    const int lg   = lane >> 4;     // k-group / row-group
    const int m0   = blockIdx.x * 64;
    const int mtMax = (m0 + 64 <= NNODES) ? 4 : 2;   // tail block has 32 rows

    // B fragments from global (fragment layout), wave-resident for whole block
    const int koff = (w >= 2) ? 128 : 0;             // waves 2,3 -> W1b
    short8 bfrag[4][4];                              // [nt][kt]
    #pragma unroll
    for (int nt = 0; nt < 4; ++nt) {
        const int cc = (w & 1) * 64 + nt * 16 + lr;  // 0..127 within half
        #pragma unroll
        for (int kt = 0; kt < 4; ++kt) {
            const int kb = koff + kt * 32 + lg * 8;
            short8 f;
            #pragma unroll
            for (int j = 0; j < 8; ++j) f[j] = (short)f2bf(W1[(long)(kb + j) * DIM + cc]);
            bfrag[nt][kt] = f;
        }
    }

    // stage x tile -> bf16 LDS (swizzled)
    {
        const int r  = tid >> 2;          // 0..63
        const int kq = (tid & 3) * 32;    // 32 k per thread
        if (m0 + r < NNODES) {
            const float* xr = &x[(long)(m0 + r) * DIM + kq];
            ushort tmp[32];
            #pragma unroll
            for (int j = 0; j < 32; ++j) tmp[j] = f2bf(xr[j]);
            #pragma unroll
            for (int i = 0; i < 4; ++i) {
                int byte = r * 256 + kq * 2 + i * 16;
                byte ^= (r & 7) << 4;
                *(short8*)(xt + byte) = *(short8*)&tmp[i * 8];
            }
        }
    }
    __syncthreads();

    const int colBase = w * 64;          // 0..255 output column base
    for (int mt = 0; mt < mtMax; ++mt) {
        short8 afrag[4];
        #pragma unroll
        for (int kt = 0; kt < 4; ++kt) {
            const int row = mt * 16 + lr;
            int byte = row * 256 + (kt * 4 + lg) * 16;
            byte ^= (row & 7) << 4;
            afrag[kt] = *(short8*)(xt + byte);
        }
        f32x4 acc[4] = {};
        #pragma unroll
        for (int nt = 0; nt < 4; ++nt)
            #pragma unroll
            for (int kt = 0; kt < 4; ++kt)
                acc[nt] = __builtin_amdgcn_mfma_f32_16x16x32_bf16(afrag[kt], bfrag[nt][kt], acc[nt], 0, 0, 0);
        #pragma unroll
        for (int nt = 0; nt < 4; ++nt) {
            const int col = colBase + nt * 16 + lr;
            #pragma unroll
            for (int r = 0; r < 4; ++r) {
                const int row = m0 + mt * 16 + lg * 4 + r;
                xab[(long)row * 256 + col] = f2bf(acc[nt][r]);
            }
        }
    }
}

// ---------------------------------------------------------------- histogram
__global__ void hist_kernel(const int* __restrict__ ei, int* __restrict__ hist) {
    int e = blockIdx.x * 256 + threadIdx.x;
    if (e < NEDGES) atomicAdd(&hist[ei[NEDGES + e]], 1);
}

// ---------------------------------------------------------------- 2-level scan
__global__ void scan1_kernel(const int* __restrict__ hist, int* __restrict__ excl,
                             int* __restrict__ bsums) {
    __shared__ int s[256];
    int tid = threadIdx.x;
    int i = blockIdx.x * 256 + tid;
    int v = (i < NNODES) ? hist[i] : 0;
    s[tid] = v;
    __syncthreads();
    for (int o = 1; o < 256; o <<= 1) {
        int t = (tid >= o) ? s[tid - o] : 0;
        __syncthreads();
        s[tid] += t;
        __syncthreads();
    }
    if (i < NNODES) excl[i] = s[tid] - v;
    if (tid == 255) bsums[blockIdx.x] = s[255];
}

__global__ void scan2_kernel(int* __restrict__ bsums) {
    __shared__ int s[512];
    int tid = threadIdx.x;
    int v = (tid < NSCAN_BLOCKS) ? bsums[tid] : 0;
    s[tid] = v;
    __syncthreads();
    for (int o = 1; o < 512; o <<= 1) {
        int t = (tid >= o) ? s[tid - o] : 0;
        __syncthreads();
        s[tid] += t;
        __syncthreads();
    }
    if (tid < NSCAN_BLOCKS) bsums[tid] = s[tid] - v;   // exclusive
}

__global__ void scan3_kernel(const int* __restrict__ excl, const int* __restrict__ bsums,
                             int* __restrict__ cursor) {
    int i = blockIdx.x * 256 + threadIdx.x;
    if (i < NNODES) cursor[i] = excl[i] + bsums[blockIdx.x];
}

// ---------------------------------------------------------------- scatter (counting sort)
__global__ void scatter_kernel(const int* __restrict__ ei, int* __restrict__ cursor,
                               int* __restrict__ sorted) {
    int e = blockIdx.x * 256 + threadIdx.x;
    if (e < NEDGES) {
        int d = ei[NEDGES + e];
        int pos = atomicAdd(&cursor[d], 1);
        sorted[pos] = e;
    }
}

// ---------------------------------------------------------------- edge phase
// h = xa[dst]+xb[src]+ea@W1c+b1 ; GN ; SiLU ; segmented-sum by dst -> atomic to out(acc)
__global__ __launch_bounds__(256) void edge_silu_kernel(
    const ushort* __restrict__ xab,
    const int* __restrict__ ei, const float* __restrict__ ea,
    const int* __restrict__ sorted,
    const float* __restrict__ W1, const float* __restrict__ b1,
    const float* __restrict__ gamma, const float* __restrict__ beta,
    float* __restrict__ out)
{
    __shared__ __align__(16) ushort ssilu[EB * 128];   // bf16, XOR-swizzled by edge row
    __shared__ float w1cs[4][4][33];                   // [coef][q][i]  bank-spread
    __shared__ float sb1s[4][33], sgs[4][33], sbts[4][33];
    __shared__ int   sdst[EB], ssrc[EB], seid[EB];
    __shared__ float sea[EB][4];

    const int tid = threadIdx.x;
    const int e0 = blockIdx.x * EB;

    if (tid < EB) {
        int id = sorted[e0 + tid];
        seid[tid] = id;
        sdst[tid] = ei[NEDGES + id];
        ssrc[tid] = ei[id];
        *(float4*)&sea[tid][0] = *(const float4*)&ea[(long)id * 4];
    }
    if (tid < 128) {
        int q = tid >> 5, i = tid & 31;
        sb1s[q][i] = b1[tid]; sgs[q][i] = gamma[tid]; sbts[q][i] = beta[tid];
        w1cs[0][q][i] = W1[256 * DIM + tid];
        w1cs[1][q][i] = W1[257 * DIM + tid];
        w1cs[2][q][i] = W1[258 * DIM + tid];
        w1cs[3][q][i] = W1[259 * DIM + tid];
    }
    __syncthreads();

    // each thread: one edge (e = tid>>2), 32 consecutive channels (q = tid&3)
    {
        const int e = tid >> 2;
        const int q = tid & 3;
        const int c0 = q * 32;
        const ushort* xaRow = &xab[(long)sdst[e] * 256 + c0];
        const ushort* xbRow = &xab[(long)ssrc[e] * 256 + 128 + c0];
        const float a0 = sea[e][0], a1 = sea[e][1], a2 = sea[e][2], a3 = sea[e][3];

        float v[32];
        #pragma unroll
        for (int i = 0; i < 4; ++i) {
            short8 va = *(const short8*)&xaRow[i * 8];
            short8 vb = *(const short8*)&xbRow[i * 8];
            #pragma unroll
            for (int j = 0; j < 8; ++j) {
                int idx = i * 8 + j;
                v[idx] = bf2f((ushort)va[j]) + bf2f((ushort)vb[j]) + sb1s[q][idx]
                       + a0 * w1cs[0][q][idx] + a1 * w1cs[1][q][idx]
                       + a2 * w1cs[2][q][idx] + a3 * w1cs[3][q][idx];
            }
        }

        // GroupNorm + SiLU: thread owns exactly 2 full groups of 16 channels
        #pragma unroll
        for (int g = 0; g < 2; ++g) {
            float sum = 0.f;
            #pragma unroll
            for (int i = 0; i < GS; ++i) sum += v[g * GS + i];
            float mean = sum * (1.f / GS);
            float var = 0.f;
            #pragma unroll
            for (int i = 0; i < GS; ++i) { float d = v[g * GS + i] - mean; var += d * d; }
            var *= (1.f / GS);
            float inv = rsqrtf(var + 1e-5f);
            #pragma unroll
            for (int i = 0; i < GS; ++i) {
                int idx = g * GS + i;
                float t = (v[idx] - mean) * inv * sgs[q][idx] + sbts[q][idx];
                v[idx] = t / (1.f + __expf(-t));
            }
        }
        // store silu as bf16, swizzled
        ushort tmp[32];
        #pragma unroll
        for (int j = 0; j < 32; ++j) tmp[j] = f2bf(v[j]);
        #pragma unroll
        for (int i = 0; i < 4; ++i) {
            int byte = e * 256 + (c0 + i * 8) * 2;
            byte ^= (e & 7) << 4;
            *(short8*)((char*)ssilu + byte) = *(short8*)&tmp[i * 8];
        }
    }
    __syncthreads();

    // segmented column-walk: thread = (channel c, half h); branch is lane-uniform
    {
        const int c = tid & 127;
        const int h = tid >> 7;
        const int eS = h * 32, eE = eS + 32;
        float r = 0.f;
        int cur = sdst[eS];
        for (int ee = eS; ee < eE; ++ee) {
            int d = sdst[ee];
            if (d != cur) {
                unsafeAtomicAdd(&out[(long)cur * DIM + c], r);
                r = 0.f; cur = d;
            }
            int byte = (ee * 256 + c * 2) ^ ((ee & 7) << 4);
            r += bf2f(*(const ushort*)((const char*)ssilu + byte));
        }
        unsafeAtomicAdd(&out[(long)cur * DIM + c], r);
    }
}

// ---------------------------------------------------------------- node GEMM2 (MFMA, in-place)
// out[n] = (acc[n] @ W2 + cnt_n*b2) / max(cnt_n,1);  acc == out, staged to LDS first
__global__ __launch_bounds__(256) void node_gemm2(float* __restrict__ out,
                                                  const float* __restrict__ W2,
                                                  const float* __restrict__ b2,
                                                  const int* __restrict__ hist) {
    __shared__ __align__(16) char at[64 * 256];   // 64 rows x 128 bf16, swizzled
    __shared__ float sb2[128];
    __shared__ int scnt[64];
    const int tid  = threadIdx.x;
    const int lane = tid & 63;
    const int w    = tid >> 6;
    const int lr   = lane & 15;
    const int lg   = lane >> 4;
    const int m0   = blockIdx.x * 64;
    const int mtMax = (m0 + 64 <= NNODES) ? 4 : 2;

    // B fragments: wave w owns cols [w*32, w*32+32)
    short8 bfrag[2][4];
    #pragma unroll
    for (int nt = 0; nt < 2; ++nt) {
        const int cc = w * 32 + nt * 16 + lr;
        #pragma unroll
        for (int kt = 0; kt < 4; ++kt) {
            const int kb = kt * 32 + lg * 8;
            short8 f;
            #pragma unroll
            for (int j = 0; j < 8; ++j) f[j] = (short)f2bf(W2[(long)(kb + j) * DIM + cc]);
            bfrag[nt][kt] = f;
        }
    }

    if (tid < 128) sb2[tid] = b2[tid];
    if (tid < 64 && m0 + tid < NNODES) scnt[tid] = hist[m0 + tid];

    // stage acc rows -> bf16 LDS (swizzled); all reads of this block's rows happen here
    {
        const int r  = tid >> 2;
        const int kq = (tid & 3) * 32;
        if (m0 + r < NNODES) {
            const float* ar = &out[(long)(m0 + r) * DIM + kq];
            ushort tmp[32];
            #pragma unroll
            for (int j = 0; j < 32; ++j) tmp[j] = f2bf(ar[j]);
            #pragma unroll
            for (int i = 0; i < 4; ++i) {
                int byte = r * 256 + kq * 2 + i * 16;
                byte ^= (r & 7) << 4;
                *(short8*)(at + byte) = *(short8*)&tmp[i * 8];
            }
        }
    }
    __syncthreads();

    for (int mt = 0; mt < mtMax; ++mt) {
        short8 afrag[4];
        #pragma unroll
        for (int kt = 0; kt < 4; ++kt) {
            const int row = mt * 16 + lr;
            int byte = row * 256 + (kt * 4 + lg) * 16;
            byte ^= (row & 7) << 4;
            afrag[kt] = *(short8*)(at + byte);
        }
        f32x4 acc[2] = {};
        #pragma unroll
        for (int nt = 0; nt < 2; ++nt)
            #pragma unroll
            for (int kt = 0; kt < 4; ++kt)
                acc[nt] = __builtin_amdgcn_mfma_f32_16x16x32_bf16(afrag[kt], bfrag[nt][kt], acc[nt], 0, 0, 0);
        #pragma unroll
        for (int nt = 0; nt < 2; ++nt) {
            const int col = w * 32 + nt * 16 + lr;
            #pragma unroll
            for (int r = 0; r < 4; ++r) {
                const int rr = mt * 16 + lg * 4 + r;
                float cnt = (float)scnt[rr];
                float sc = 1.f / fmaxf(cnt, 1.f);
                out[(long)(m0 + rr) * DIM + col] = (acc[nt][r] + cnt * sb2[col]) * sc;
            }
        }
    }
}

// ---------------------------------------------------------------- launch
extern "C" void kernel_launch(void* const* d_in, const int* in_sizes, int n_in,
                              void* d_out, int out_size, void* d_ws, size_t ws_size,
                              hipStream_t stream) {
    const float* x     = (const float*)d_in[0];
    const int*   ei    = (const int*)  d_in[1];
    const float* ea    = (const float*)d_in[2];
    const float* W1    = (const float*)d_in[3];
    const float* b1    = (const float*)d_in[4];
    const float* gamma = (const float*)d_in[5];
    const float* beta  = (const float*)d_in[6];
    const float* W2    = (const float*)d_in[7];
    const float* b2    = (const float*)d_in[8];
    float* out = (float*)d_out;

    char* ws = (char*)d_ws;
    size_t off = 0;
    ushort* xab   = (ushort*)(ws + off); off += (size_t)NNODES * 256 * sizeof(ushort);
    int*    hist  = (int*)   (ws + off); off += (size_t)NNODES * sizeof(int);
    int*    excl  = (int*)   (ws + off); off += (size_t)NNODES * sizeof(int);
    int*    cursor= (int*)   (ws + off); off += (size_t)NNODES * sizeof(int);
    int*    bsums = (int*)   (ws + off); off += 512 * sizeof(int);
    int*    sorted= (int*)   (ws + off); off += (size_t)NEDGES * sizeof(int);

    zero_kernel<<<2048, 256, 0, stream>>>(out, hist);
    node_gemm1<<<G1_BLOCKS, 256, 0, stream>>>(x, W1, xab);
    hist_kernel<<<(NEDGES + 255) / 256, 256, 0, stream>>>(ei, hist);
    scan1_kernel<<<NSCAN_BLOCKS, 256, 0, stream>>>(hist, excl, bsums);
    scan2_kernel<<<1, 512, 0, stream>>>(bsums);
    scan3_kernel<<<NSCAN_BLOCKS, 256, 0, stream>>>(excl, bsums, cursor);
    scatter_kernel<<<(NEDGES + 255) / 256, 256, 0, stream>>>(ei, cursor, sorted);
    edge_silu_kernel<<<NEDGES / EB, 256, 0, stream>>>(xab, ei, ea, sorted,
                                                      W1, b1, gamma, beta, out);
    node_gemm2<<<G1_BLOCKS, 256, 0, stream>>>(out, W2, b2, hist);
}